// Round 1
// baseline (225.156 us; speedup 1.0000x reference)
//
#include <hip/hip_runtime.h>
#include <math.h>

#define NB 128      // batch
#define LQ 32       // query tokens
#define LD 180      // doc tokens
#define DD 128      // feature dim
#define NW 8        // nway
#define PAD 129     // LDS tile row pitch (floats), odd -> conflict-free b32 col reads
#define LDROWS 192  // padded token rows (multiple of 32 for the 6x l-tiling)

// One block per (b,w): stage masked doc tile to LDS + per-feature ssq,
// fold doc-column inv-norms and query row inv-norms into q', then
// register-tiled sim GEMM + maxsim reduction.
__global__ __launch_bounds__(256) void maxsim_kernel(
    const float* __restrict__ qreps,   // [B][LQ][DD]
    const float* __restrict__ dreps,   // [B][NW][LD][DD]
    const int*   __restrict__ dmask,   // [B][NW][LD]
    float*       __restrict__ scores)  // [B][NW]
{
    __shared__ float s_tile[LDROWS * PAD];   // 99072 B (rows >= LD uninitialized, never used)
    __shared__ float s_q[LQ * DD];           // 16384 B
    __shared__ float s_ssq[8 * DD];          // 4096 B
    __shared__ float s_dinv[DD];
    __shared__ float s_qinv[LQ];
    __shared__ float s_rowmax[LQ];

    const int t  = threadIdx.x;
    const int bw = blockIdx.x;
    const int b  = bw >> 3;

    // ---- Phase 1: load doc tile (masked) to LDS, accumulate per-feature ssq ----
    const float4* doc4 = (const float4*)(dreps + (size_t)bw * LD * DD);
    const int*    mrow = dmask + bw * LD;
    const int d0 = (4 * t) & 127;     // fixed feature quad for this thread
    const int l0 = (4 * t) >> 7;      // starting token row (0..7)
    float sx = 0.f, sy = 0.f, sz = 0.f, sw = 0.f;
    for (int l = l0; l < LD; l += 8) {
        float4 v = doc4[l * (DD / 4) + (d0 >> 2)];
        float mk = (float)mrow[l];
        v.x *= mk; v.y *= mk; v.z *= mk; v.w *= mk;
        int base = l * PAD + d0;
        s_tile[base + 0] = v.x; s_tile[base + 1] = v.y;
        s_tile[base + 2] = v.z; s_tile[base + 3] = v.w;
        sx += v.x * v.x; sy += v.y * v.y; sz += v.z * v.z; sw += v.w * v.w;
    }
    {
        int base = (t >> 5) * DD + d0;
        s_ssq[base + 0] = sx; s_ssq[base + 1] = sy;
        s_ssq[base + 2] = sz; s_ssq[base + 3] = sw;
    }

    // ---- Phase 2a: load q tile (coalesced float4) ----
    const float4* q4 = (const float4*)(qreps + (size_t)b * LQ * DD);
    for (int f = t; f < (LQ * DD) / 4; f += 256) {
        ((float4*)s_q)[f] = q4[f];
    }
    __syncthreads();

    // per-feature doc inv-norms
    if (t < DD) {
        float tot = 0.f;
        #pragma unroll
        for (int g = 0; g < 8; ++g) tot += s_ssq[g * DD + t];
        s_dinv[t] = 1.0f / fmaxf(sqrtf(tot), 1e-12f);
    }
    // query row inv-norms: 8 threads per row, 16 elems each
    {
        int r = t >> 3, sub = t & 7;
        const float* qr = s_q + r * DD + sub * 16;
        float ss = 0.f;
        #pragma unroll
        for (int k = 0; k < 16; ++k) ss += qr[k] * qr[k];
        ss += __shfl_xor(ss, 4);
        ss += __shfl_xor(ss, 2);
        ss += __shfl_xor(ss, 1);
        if (sub == 0) s_qinv[r] = 1.0f / fmaxf(sqrtf(ss), 1e-12f);
    }
    __syncthreads();

    // fold both norms into q'
    for (int e = t; e < LQ * DD; e += 256) {
        s_q[e] *= s_qinv[e >> 7] * s_dinv[e & 127];
    }
    __syncthreads();

    // ---- Phase 3: sim GEMM (32q x 180l over 128d) + maxsim ----
    const int i = t >> 5;   // q-group 0..7   -> rows {i, i+8, i+16, i+24}
    const int j = t & 31;   // l-group 0..31  -> cols {j, j+32, ..., j+160}
    float acc[4][6];
    #pragma unroll
    for (int k = 0; k < 4; ++k)
        #pragma unroll
        for (int m = 0; m < 6; ++m) acc[k][m] = 0.f;

    const float* qr0 = s_q + (i + 0)  * DD;
    const float* qr1 = s_q + (i + 8)  * DD;
    const float* qr2 = s_q + (i + 16) * DD;
    const float* qr3 = s_q + (i + 24) * DD;

    for (int d = 0; d < DD; d += 4) {
        float4 qa = *(const float4*)(qr0 + d);
        float4 qb = *(const float4*)(qr1 + d);
        float4 qc = *(const float4*)(qr2 + d);
        float4 qd = *(const float4*)(qr3 + d);
        #pragma unroll
        for (int dd = 0; dd < 4; ++dd) {
            float q0 = (&qa.x)[dd];
            float q1 = (&qb.x)[dd];
            float q2 = (&qc.x)[dd];
            float q3 = (&qd.x)[dd];
            #pragma unroll
            for (int m = 0; m < 6; ++m) {
                float tv = s_tile[(j + 32 * m) * PAD + d + dd];
                acc[0][m] += q0 * tv;
                acc[1][m] += q1 * tv;
                acc[2][m] += q2 * tv;
                acc[3][m] += q3 * tv;
            }
        }
    }

    // per-thread max over valid l, then reduce across the 32 j-lanes
    float pm[4];
    #pragma unroll
    for (int k = 0; k < 4; ++k) {
        pm[k] = acc[k][0];                       // l = j < 180 always valid
        #pragma unroll
        for (int m = 1; m < 6; ++m) {
            if (j + 32 * m < LD) pm[k] = fmaxf(pm[k], acc[k][m]);
        }
    }
    #pragma unroll
    for (int off = 16; off > 0; off >>= 1) {
        #pragma unroll
        for (int k = 0; k < 4; ++k)
            pm[k] = fmaxf(pm[k], __shfl_xor(pm[k], off, 32));
    }
    if (j == 0) {
        #pragma unroll
        for (int k = 0; k < 4; ++k) s_rowmax[i + 8 * k] = pm[k];
    }
    __syncthreads();

    if (t < 32) {
        float v = s_rowmax[t];
        #pragma unroll
        for (int off = 16; off > 0; off >>= 1) v += __shfl_xor(v, off, 32);
        if (t == 0) scores[bw] = v;
    }
}

// log-softmax over W=8 + KLDiv(log_target=True, batchmean); one thread per b.
__global__ __launch_bounds__(NB) void finish_kernel(
    const float* __restrict__ scores,   // [B][NW]
    const float* __restrict__ labels,   // [B][NW]
    float*       __restrict__ out)      // [1]
{
    __shared__ float s_part[2];
    const int t = threadIdx.x;
    const float* sr = scores + t * NW;
    const float* lr = labels + t * NW;

    float s[NW];
    float m = -INFINITY;
    #pragma unroll
    for (int w = 0; w < NW; ++w) { s[w] = sr[w]; m = fmaxf(m, s[w]); }
    float se = 0.f;
    #pragma unroll
    for (int w = 0; w < NW; ++w) se += expf(s[w] - m);
    float lse = logf(se) + m;

    float term = 0.f;
    #pragma unroll
    for (int w = 0; w < NW; ++w) {
        float lw = lr[w];
        term += expf(lw) * (lw - (s[w] - lse));
    }
    // reduce 128 threads = 2 waves
    #pragma unroll
    for (int off = 32; off > 0; off >>= 1) term += __shfl_xor(term, off);
    if ((t & 63) == 0) s_part[t >> 6] = term;
    __syncthreads();
    if (t == 0) out[0] = (s_part[0] + s_part[1]) / (float)NB;
}

extern "C" void kernel_launch(void* const* d_in, const int* in_sizes, int n_in,
                              void* d_out, int out_size, void* d_ws, size_t ws_size,
                              hipStream_t stream) {
    const float* qreps  = (const float*)d_in[0];
    const float* dreps  = (const float*)d_in[1];
    const int*   dmask  = (const int*)d_in[2];
    const float* labels = (const float*)d_in[3];
    float* out    = (float*)d_out;
    float* scores = (float*)d_ws;   // B*NW floats

    maxsim_kernel<<<NB * NW, 256, 0, stream>>>(qreps, dreps, dmask, scores);
    finish_kernel<<<1, NB, 0, stream>>>(scores, labels, out);
}

// Round 2
// 188.389 us; speedup vs baseline: 1.1952x; 1.1952x over previous
//
#include <hip/hip_runtime.h>
#include <math.h>

#define NB 128      // batch
#define LQ 32       // query tokens
#define LD 180      // doc tokens
#define DD 128      // feature dim
#define NW 8        // nway
#define NBW (NB*NW)
#define TP 36       // LDS row pitch in words (144 B: 16B-aligned, bank-rotating)

// ---------- Kernel A: per-feature masked column inv-norms ----------
// grid NBW x 256. dinv[bw][d] = 1/max(||masked col d||, 1e-12)
__global__ __launch_bounds__(256) void dnorm_kernel(
    const float* __restrict__ dreps, const int* __restrict__ dmask,
    float* __restrict__ dinv)
{
    __shared__ float s_ssq[8 * DD];
    const int t = threadIdx.x, bw = blockIdx.x;
    const float4* doc4 = (const float4*)(dreps + (size_t)bw * LD * DD);
    const int* mrow = dmask + bw * LD;
    const int d4 = t & 31, rg = t >> 5;
    float sx = 0.f, sy = 0.f, sz = 0.f, sw = 0.f;
    for (int l = rg; l < LD; l += 8) {
        float4 v = doc4[l * 32 + d4];
        float m = (float)mrow[l];
        sx += m * v.x * v.x; sy += m * v.y * v.y;
        sz += m * v.z * v.z; sw += m * v.w * v.w;
    }
    float4 ss; ss.x = sx; ss.y = sy; ss.z = sz; ss.w = sw;
    *(float4*)&s_ssq[rg * DD + 4 * d4] = ss;
    __syncthreads();
    if (t < DD) {
        float tot = 0.f;
        #pragma unroll
        for (int g = 0; g < 8; ++g) tot += s_ssq[g * DD + t];
        dinv[bw * DD + t] = 1.0f / fmaxf(sqrtf(tot), 1e-12f);
    }
}

// ---------- Kernel A2: query row inv-norms ----------
// grid NB x 256. qinv[b][r] = 1/max(||q_row||, 1e-12)
__global__ __launch_bounds__(256) void qnorm_kernel(
    const float* __restrict__ qreps, float* __restrict__ qinv)
{
    const int t = threadIdx.x, b = blockIdx.x;
    const int r = t >> 3, sub = t & 7;
    const float4* qr = (const float4*)(qreps + (size_t)b * LQ * DD + r * DD + sub * 16);
    float ss = 0.f;
    #pragma unroll
    for (int k = 0; k < 4; ++k) {
        float4 v = qr[k];
        ss += v.x * v.x + v.y * v.y + v.z * v.z + v.w * v.w;
    }
    ss += __shfl_xor(ss, 4);
    ss += __shfl_xor(ss, 2);
    ss += __shfl_xor(ss, 1);
    if (sub == 0) qinv[b * LQ + r] = 1.0f / fmaxf(sqrtf(ss), 1e-12f);
}

// ---------- Kernel B: MaxSim GEMM, d-chunked LDS staging ----------
// grid NBW x 128 (2 waves). Wave splits columns: w0 cols 0..95, w1 cols 84..179
// (overlap harmless under max). Per lane: R=8 q-rows x C=6 doc-cols.
// Mask applied at epilogue only: sim = m[l] * sim_unmasked (exact identity).
__global__ __launch_bounds__(128, 2) void maxsim_kernel(
    const float* __restrict__ qreps, const float* __restrict__ dreps,
    const int* __restrict__ dmask, const float* __restrict__ dinv,
    const float* __restrict__ qinv, float* __restrict__ scores)
{
    __shared__ float s_tile[LD * TP];   // 25920 B
    __shared__ float s_q[LQ * TP];      //  4608 B
    __shared__ float s_pm[2][LQ];

    const int t = threadIdx.x, bw = blockIdx.x, b = bw >> 3;
    const int lane = t & 63, wave = t >> 6;
    const int rowg = lane >> 4;          // 0..3  -> rows rowg+4k
    const int colg = lane & 15;          // 0..15 -> cols colbase+colg+16c
    const int colbase = wave * 84;

    const float4* doc4  = (const float4*)(dreps + (size_t)bw * LD * DD);
    const float4* q4g   = (const float4*)(qreps + (size_t)b * LQ * DD);
    const float4* dinv4 = (const float4*)(dinv + (size_t)bw * DD);
    const float*  qinvb = qinv + b * LQ;

    float acc[8][6];
    #pragma unroll
    for (int k = 0; k < 8; ++k)
        #pragma unroll
        for (int c = 0; c < 6; ++c) acc[k][c] = 0.f;

    for (int cc = 0; cc < 4; ++cc) {          // d-chunks of 32 features
        if (cc) __syncthreads();
        // stage q' slice [32 rows][32 d] = 256 float4
        {
            int f = t;
            #pragma unroll
            for (int s = 0; s < 2; ++s, f += 128) {
                int r = f >> 3, d4 = f & 7;
                float4 v  = q4g[r * 32 + cc * 8 + d4];
                float4 di = dinv4[cc * 8 + d4];
                float  qi = qinvb[r];
                v.x *= qi * di.x; v.y *= qi * di.y;
                v.z *= qi * di.z; v.w *= qi * di.w;
                *(float4*)&s_q[r * TP + 4 * d4] = v;
            }
        }
        // stage doc tile slice [180 rows][32 d] = 1440 float4
        {
            int f = t;
            #pragma unroll
            for (int s = 0; s < 12; ++s, f += 128) {
                if (f < LD * 8) {
                    int l = f >> 3, d4 = f & 7;
                    *(float4*)&s_tile[l * TP + 4 * d4] = doc4[l * 32 + cc * 8 + d4];
                }
            }
        }
        __syncthreads();

        #pragma unroll
        for (int dq = 0; dq < 8; ++dq) {      // 8 d-quads per chunk
            float4 qv[8], tv[6];
            #pragma unroll
            for (int k = 0; k < 8; ++k)
                qv[k] = *(const float4*)&s_q[(rowg + 4 * k) * TP + 4 * dq];
            #pragma unroll
            for (int c = 0; c < 6; ++c)
                tv[c] = *(const float4*)&s_tile[(colbase + colg + 16 * c) * TP + 4 * dq];
            #pragma unroll
            for (int k = 0; k < 8; ++k)
                #pragma unroll
                for (int c = 0; c < 6; ++c) {
                    acc[k][c] = fmaf(qv[k].x, tv[c].x, acc[k][c]);
                    acc[k][c] = fmaf(qv[k].y, tv[c].y, acc[k][c]);
                    acc[k][c] = fmaf(qv[k].z, tv[c].z, acc[k][c]);
                    acc[k][c] = fmaf(qv[k].w, tv[c].w, acc[k][c]);
                }
        }
    }

    // ---- epilogue: mask, per-row max over cols, cross-lane/wave reduce ----
    int msk[6];
    #pragma unroll
    for (int c = 0; c < 6; ++c)
        msk[c] = dmask[bw * LD + colbase + colg + 16 * c];

    float pm[8];
    #pragma unroll
    for (int k = 0; k < 8; ++k) {
        float m = -INFINITY;
        #pragma unroll
        for (int c = 0; c < 6; ++c) {
            float cand = msk[c] ? acc[k][c] : 0.0f;   // masked col -> sim 0
            m = fmaxf(m, cand);
        }
        pm[k] = m;
    }
    // reduce over the 16 colg lanes (stays within the 16-lane group)
    #pragma unroll
    for (int off = 8; off >= 1; off >>= 1)
        #pragma unroll
        for (int k = 0; k < 8; ++k)
            pm[k] = fmaxf(pm[k], __shfl_xor(pm[k], off));
    if (colg == 0) {
        #pragma unroll
        for (int k = 0; k < 8; ++k) s_pm[wave][rowg + 4 * k] = pm[k];
    }
    __syncthreads();
    if (t < LQ) {
        float v = fmaxf(s_pm[0][t], s_pm[1][t]);
        #pragma unroll
        for (int off = 16; off >= 1; off >>= 1) v += __shfl_xor(v, off);
        if (t == 0) scores[bw] = v;
    }
}

// ---------- finisher: log-softmax over W + KLDiv(log_target, batchmean) ----------
__global__ __launch_bounds__(NB) void finish_kernel(
    const float* __restrict__ scores, const float* __restrict__ labels,
    float* __restrict__ out)
{
    __shared__ float s_part[2];
    const int t = threadIdx.x;
    const float* sr = scores + t * NW;
    const float* lr = labels + t * NW;

    float s[NW];
    float m = -INFINITY;
    #pragma unroll
    for (int w = 0; w < NW; ++w) { s[w] = sr[w]; m = fmaxf(m, s[w]); }
    float se = 0.f;
    #pragma unroll
    for (int w = 0; w < NW; ++w) se += expf(s[w] - m);
    float lse = logf(se) + m;

    float term = 0.f;
    #pragma unroll
    for (int w = 0; w < NW; ++w) {
        float lw = lr[w];
        term += expf(lw) * (lw - (s[w] - lse));
    }
    #pragma unroll
    for (int off = 32; off > 0; off >>= 1) term += __shfl_xor(term, off);
    if ((t & 63) == 0) s_part[t >> 6] = term;
    __syncthreads();
    if (t == 0) out[0] = (s_part[0] + s_part[1]) / (float)NB;
}

extern "C" void kernel_launch(void* const* d_in, const int* in_sizes, int n_in,
                              void* d_out, int out_size, void* d_ws, size_t ws_size,
                              hipStream_t stream) {
    const float* qreps  = (const float*)d_in[0];
    const float* dreps  = (const float*)d_in[1];
    const int*   dmask  = (const int*)d_in[2];
    const float* labels = (const float*)d_in[3];
    float* out = (float*)d_out;

    float* scores = (float*)d_ws;                 // NBW floats
    float* dinv   = scores + NBW;                 // NBW*DD floats
    float* qinv   = dinv + (size_t)NBW * DD;      // NB*LQ floats

    dnorm_kernel<<<NBW, 256, 0, stream>>>(dreps, dmask, dinv);
    qnorm_kernel<<<NB, 256, 0, stream>>>(qreps, qinv);
    maxsim_kernel<<<NBW, 128, 0, stream>>>(qreps, dreps, dmask, dinv, qinv, scores);
    finish_kernel<<<1, NB, 0, stream>>>(scores, labels, out);
}

// Round 3
// 180.852 us; speedup vs baseline: 1.2450x; 1.0417x over previous
//
#include <hip/hip_runtime.h>
#include <math.h>

#define NB 128      // batch
#define LQ 32       // query tokens
#define LD 180      // doc tokens
#define DD 128      // feature dim
#define NW 8        // nway
#define NBW (NB*NW)
#define TP 36       // LDS row pitch in words (144 B: 16B-aligned, bank-rotating)

// ---------- Query row inv-norms ----------
__global__ __launch_bounds__(256) void qnorm_kernel(
    const float* __restrict__ qreps, float* __restrict__ qinv)
{
    const int t = threadIdx.x, b = blockIdx.x;
    const int r = t >> 3, sub = t & 7;
    const float4* qr = (const float4*)(qreps + (size_t)b * LQ * DD + r * DD + sub * 16);
    float ss = 0.f;
    #pragma unroll
    for (int k = 0; k < 4; ++k) {
        float4 v = qr[k];
        ss += v.x * v.x + v.y * v.y + v.z * v.z + v.w * v.w;
    }
    ss += __shfl_xor(ss, 4);
    ss += __shfl_xor(ss, 2);
    ss += __shfl_xor(ss, 1);
    if (sub == 0) qinv[b * LQ + r] = 1.0f / fmaxf(sqrtf(ss), 1e-12f);
}

// ---------- MaxSim: single pass over dreps, fused column-norm ----------
// grid NBW x 128 (2 waves). Doc tile streamed in 4 d-chunks of 32 features;
// per-chunk: stage masked tile slice + per-feature ssq (each staging thread
// owns feature-quad d4=t&7), reduce to dinv[32], fold into q' slice, GEMM.
// Wave0 cols 0..95, wave1 cols 84..179 (overlap harmless under max).
// Per lane: R=8 q-rows x C=6 doc-cols.
__global__ __launch_bounds__(128, 2) void maxsim_kernel(
    const float* __restrict__ qreps, const float* __restrict__ dreps,
    const int* __restrict__ dmask, const float* __restrict__ qinv,
    float* __restrict__ scores)
{
    __shared__ float s_tile[LD * TP];   // 25920 B
    __shared__ float s_q[LQ * TP];      //  4608 B
    __shared__ float s_ssq[16 * 32];    //  2048 B
    __shared__ float s_dinv[32];
    __shared__ float s_pm[2][LQ];

    const int t = threadIdx.x, bw = blockIdx.x, b = bw >> 3;
    const int lane = t & 63, wave = t >> 6;
    const int rowg = lane >> 4;          // 0..3  -> rows rowg+4k
    const int colg = lane & 15;          // 0..15 -> cols colbase+colg+16c
    const int colbase = wave * 84;

    const float4* doc4  = (const float4*)(dreps + (size_t)bw * LD * DD);
    const float4* q4g   = (const float4*)(qreps + (size_t)b * LQ * DD);
    const float*  qinvb = qinv + b * LQ;
    const int*    mrow  = dmask + bw * LD;

    const int d4 = t & 7;       // this thread's feature-quad within the chunk
    const int rbase = t >> 3;   // 0..15

    // masks for this thread's staging rows (l = rbase + 16s), loaded once
    float mk[12];
    #pragma unroll
    for (int s = 0; s < 12; ++s) {
        int l = rbase + 16 * s;
        mk[s] = (l < LD) ? (float)mrow[l] : 0.0f;
    }

    float acc[8][6];
    #pragma unroll
    for (int k = 0; k < 8; ++k)
        #pragma unroll
        for (int c = 0; c < 6; ++c) acc[k][c] = 0.f;

    for (int cc = 0; cc < 4; ++cc) {
        if (cc) __syncthreads();   // previous GEMM done reading LDS

        // stage q slice (qinv folded; dinv folded later): 2 float4 per thread
        {
            #pragma unroll
            for (int s = 0; s < 2; ++s) {
                int r = rbase + 16 * s;
                float4 v = q4g[r * 32 + cc * 8 + d4];
                float qi = qinvb[r];
                v.x *= qi; v.y *= qi; v.z *= qi; v.w *= qi;
                *(float4*)&s_q[r * TP + 4 * d4] = v;
            }
        }
        // stage masked doc slice + per-feature-quad ssq
        float4 pssq = make_float4(0.f, 0.f, 0.f, 0.f);
        #pragma unroll
        for (int s = 0; s < 12; ++s) {
            int l = rbase + 16 * s;
            if (s < 11 || t < 32) {
                float4 v = doc4[l * 32 + cc * 8 + d4];
                float m = mk[s];
                v.x *= m; v.y *= m; v.z *= m; v.w *= m;
                pssq.x += v.x * v.x; pssq.y += v.y * v.y;
                pssq.z += v.z * v.z; pssq.w += v.w * v.w;
                *(float4*)&s_tile[l * TP + 4 * d4] = v;
            }
        }
        *(float4*)&s_ssq[rbase * 32 + 4 * d4] = pssq;
        __syncthreads();

        if (t < 32) {
            float tot = 0.f;
            #pragma unroll
            for (int g = 0; g < 16; ++g) tot += s_ssq[g * 32 + t];
            s_dinv[t] = 1.0f / fmaxf(sqrtf(tot), 1e-12f);
        }
        __syncthreads();

        // fold dinv into the q'-slice entries this thread staged
        {
            float4 di = *(const float4*)&s_dinv[4 * d4];
            #pragma unroll
            for (int s = 0; s < 2; ++s) {
                int r = rbase + 16 * s;
                float4 v = *(float4*)&s_q[r * TP + 4 * d4];
                v.x *= di.x; v.y *= di.y; v.z *= di.z; v.w *= di.w;
                *(float4*)&s_q[r * TP + 4 * d4] = v;
            }
        }
        __syncthreads();

        // GEMM on this chunk
        #pragma unroll
        for (int dq = 0; dq < 8; ++dq) {
            float4 qv[8], tv[6];
            #pragma unroll
            for (int k = 0; k < 8; ++k)
                qv[k] = *(const float4*)&s_q[(rowg + 4 * k) * TP + 4 * dq];
            #pragma unroll
            for (int c = 0; c < 6; ++c)
                tv[c] = *(const float4*)&s_tile[(colbase + colg + 16 * c) * TP + 4 * dq];
            #pragma unroll
            for (int k = 0; k < 8; ++k)
                #pragma unroll
                for (int c = 0; c < 6; ++c) {
                    acc[k][c] = fmaf(qv[k].x, tv[c].x, acc[k][c]);
                    acc[k][c] = fmaf(qv[k].y, tv[c].y, acc[k][c]);
                    acc[k][c] = fmaf(qv[k].z, tv[c].z, acc[k][c]);
                    acc[k][c] = fmaf(qv[k].w, tv[c].w, acc[k][c]);
                }
        }
    }

    // ---- epilogue: per-row max over cols (masked cols are exactly 0) ----
    float pm[8];
    #pragma unroll
    for (int k = 0; k < 8; ++k) {
        float m = acc[k][0];
        #pragma unroll
        for (int c = 1; c < 6; ++c) m = fmaxf(m, acc[k][c]);
        pm[k] = m;
    }
    #pragma unroll
    for (int off = 8; off >= 1; off >>= 1)
        #pragma unroll
        for (int k = 0; k < 8; ++k)
            pm[k] = fmaxf(pm[k], __shfl_xor(pm[k], off));
    if (colg == 0) {
        #pragma unroll
        for (int k = 0; k < 8; ++k) s_pm[wave][rowg + 4 * k] = pm[k];
    }
    __syncthreads();
    if (t < LQ) {
        float v = fmaxf(s_pm[0][t], s_pm[1][t]);
        #pragma unroll
        for (int off = 16; off >= 1; off >>= 1) v += __shfl_xor(v, off);
        if (t == 0) scores[bw] = v;
    }
}

// ---------- finisher: log-softmax over W + KLDiv(log_target, batchmean) ----------
__global__ __launch_bounds__(NB) void finish_kernel(
    const float* __restrict__ scores, const float* __restrict__ labels,
    float* __restrict__ out)
{
    __shared__ float s_part[2];
    const int t = threadIdx.x;
    const float* sr = scores + t * NW;
    const float* lr = labels + t * NW;

    float s[NW];
    float m = -INFINITY;
    #pragma unroll
    for (int w = 0; w < NW; ++w) { s[w] = sr[w]; m = fmaxf(m, s[w]); }
    float se = 0.f;
    #pragma unroll
    for (int w = 0; w < NW; ++w) se += expf(s[w] - m);
    float lse = logf(se) + m;

    float term = 0.f;
    #pragma unroll
    for (int w = 0; w < NW; ++w) {
        float lw = lr[w];
        term += expf(lw) * (lw - (s[w] - lse));
    }
    #pragma unroll
    for (int off = 32; off > 0; off >>= 1) term += __shfl_xor(term, off);
    if ((t & 63) == 0) s_part[t >> 6] = term;
    __syncthreads();
    if (t == 0) out[0] = (s_part[0] + s_part[1]) / (float)NB;
}

extern "C" void kernel_launch(void* const* d_in, const int* in_sizes, int n_in,
                              void* d_out, int out_size, void* d_ws, size_t ws_size,
                              hipStream_t stream) {
    const float* qreps  = (const float*)d_in[0];
    const float* dreps  = (const float*)d_in[1];
    const int*   dmask  = (const int*)d_in[2];
    const float* labels = (const float*)d_in[3];
    float* out = (float*)d_out;

    float* scores = (float*)d_ws;       // NBW floats
    float* qinv   = scores + NBW;       // NB*LQ floats

    qnorm_kernel<<<NB, 256, 0, stream>>>(qreps, qinv);
    maxsim_kernel<<<NBW, 128, 0, stream>>>(qreps, dreps, dmask, qinv, scores);
    finish_kernel<<<1, NB, 0, stream>>>(scores, labels, out);
}

// Round 4
// 156.949 us; speedup vs baseline: 1.4346x; 1.1523x over previous
//
#include <hip/hip_runtime.h>
#include <math.h>
#include <stdint.h>

#define NB 128      // batch
#define LQ 32       // query tokens
#define LD 180      // doc tokens
#define DD 128      // feature dim
#define NW 8        // nway
#define NBW (NB*NW)
#define PB 40       // bf16 row pitch (80 B: 16B-aligned rows, min bank aliasing)
#define LROWS 192   // doc rows padded to 6 tiles of 32 (pad rows zeroed)

typedef __attribute__((ext_vector_type(8)))  short short8v;
typedef __attribute__((ext_vector_type(16))) float f32x16;

static __device__ __forceinline__ short bf16_rne(float f) {
    uint32_t u = __float_as_uint(f);
    uint32_t r = (u + 0x7fffu + ((u >> 16) & 1u)) >> 16;
    return (short)r;
}
static __device__ __forceinline__ float bf16_f32(short h) {
    return __uint_as_float(((uint32_t)(uint16_t)h) << 16);
}

// ---------- Query row inv-norms ----------
__global__ __launch_bounds__(256) void qnorm_kernel(
    const float* __restrict__ qreps, float* __restrict__ qinv)
{
    const int t = threadIdx.x, b = blockIdx.x;
    const int r = t >> 3, sub = t & 7;
    const float4* qr = (const float4*)(qreps + (size_t)b * LQ * DD + r * DD + sub * 16);
    float ss = 0.f;
    #pragma unroll
    for (int k = 0; k < 4; ++k) {
        float4 v = qr[k];
        ss += v.x * v.x + v.y * v.y + v.z * v.z + v.w * v.w;
    }
    ss += __shfl_xor(ss, 4);
    ss += __shfl_xor(ss, 2);
    ss += __shfl_xor(ss, 1);
    if (sub == 0) qinv[b * LQ + r] = 1.0f / fmaxf(sqrtf(ss), 1e-12f);
}

// ---------- MaxSim: single pass over dreps, fused column-norm, split-bf16 MFMA ----------
// grid NBW x 256 (4 waves). Doc streamed in 4 d-chunks of 32; per chunk:
// stage masked doc as bf16 hi/lo planes + f32 ssq, reduce dinv, fold
// qinv*dinv into q' hi/lo planes, then 32x32x16 bf16 MFMA (hh + hl + lh).
// Wave w owns n-tiles {w, w+4<6}. C/D layout: col=lane&31 (doc token),
// row=(reg&3)+8*(reg>>2)+4*(lane>>5) (q row) [m101-verified].
__global__ __launch_bounds__(256, 4) void maxsim_kernel(
    const float* __restrict__ qreps, const float* __restrict__ dreps,
    const int* __restrict__ dmask, const float* __restrict__ qinv,
    float* __restrict__ scores)
{
    __shared__ short s_dh[LROWS * PB];   // 15360 B
    __shared__ short s_dl[LROWS * PB];   // 15360 B
    __shared__ short s_qh[LQ * PB];      //  2560 B
    __shared__ short s_ql[LQ * PB];      //  2560 B
    __shared__ float s_ssq[32 * 32];     //  4096 B
    __shared__ float s_dinv[32];
    __shared__ float s_pm[4][LQ];        //   512 B   (total 40576 B -> 4 blk/CU)

    const int t = threadIdx.x, bw = blockIdx.x, b = bw >> 3;
    const int lane = t & 63, wave = t >> 6;
    const int d4 = t & 7;        // feature quad within chunk
    const int rbase = t >> 3;    // 0..31: doc-row phase / q row
    const int lh = lane >> 5;    // k-half
    const int l31 = lane & 31;

    const float4* doc4  = (const float4*)(dreps + (size_t)bw * LD * DD);
    const float4* q4g   = (const float4*)(qreps + (size_t)b * LQ * DD);
    const float*  qinvb = qinv + b * LQ;
    const int*    mrow  = dmask + bw * LD;

    // per-thread doc row masks (rows rbase + 32s)
    float mk[6];
    #pragma unroll
    for (int s = 0; s < 6; ++s) {
        int l = rbase + 32 * s;
        mk[s] = (l < LD) ? (float)mrow[l] : 0.0f;
    }

    f32x16 acc0 = {};
    f32x16 acc1 = {};

    for (int cc = 0; cc < 4; ++cc) {
        if (cc) __syncthreads();          // previous GEMM done with LDS

        // prefetch this thread's q float4 (used after dinv is ready)
        float4 qv = q4g[rbase * 32 + cc * 8 + d4];

        // ---- stage masked doc slice as hi/lo bf16 + f32 ssq ----
        float4 pssq = make_float4(0.f, 0.f, 0.f, 0.f);
        #pragma unroll
        for (int s = 0; s < 6; ++s) {
            int l = rbase + 32 * s;
            if (l < LD) {
                float4 v = doc4[l * 32 + cc * 8 + d4];
                float m = mk[s];
                v.x *= m; v.y *= m; v.z *= m; v.w *= m;
                pssq.x += v.x * v.x; pssq.y += v.y * v.y;
                pssq.z += v.z * v.z; pssq.w += v.w * v.w;
                short4 h, lo;
                h.x = bf16_rne(v.x); h.y = bf16_rne(v.y);
                h.z = bf16_rne(v.z); h.w = bf16_rne(v.w);
                lo.x = bf16_rne(v.x - bf16_f32(h.x));
                lo.y = bf16_rne(v.y - bf16_f32(h.y));
                lo.z = bf16_rne(v.z - bf16_f32(h.z));
                lo.w = bf16_rne(v.w - bf16_f32(h.w));
                *(short4*)&s_dh[l * PB + 4 * d4] = h;
                *(short4*)&s_dl[l * PB + 4 * d4] = lo;
            } else {                       // pad rows 180..191 -> sim 0
                short4 z = make_short4(0, 0, 0, 0);
                *(short4*)&s_dh[l * PB + 4 * d4] = z;
                *(short4*)&s_dl[l * PB + 4 * d4] = z;
            }
        }
        *(float4*)&s_ssq[rbase * 32 + 4 * d4] = pssq;
        __syncthreads();

        // ---- per-feature inv-norms for this chunk ----
        if (t < 32) {
            float tot = 0.f;
            #pragma unroll
            for (int g = 0; g < 32; ++g) tot += s_ssq[g * 32 + t];
            s_dinv[t] = 1.0f / fmaxf(sqrtf(tot), 1e-12f);
        }
        __syncthreads();

        // ---- fold qinv*dinv into q', split to hi/lo planes ----
        {
            float qi = qinvb[rbase];
            float4 di = *(const float4*)&s_dinv[4 * d4];
            qv.x *= qi * di.x; qv.y *= qi * di.y;
            qv.z *= qi * di.z; qv.w *= qi * di.w;
            short4 h, lo;
            h.x = bf16_rne(qv.x); h.y = bf16_rne(qv.y);
            h.z = bf16_rne(qv.z); h.w = bf16_rne(qv.w);
            lo.x = bf16_rne(qv.x - bf16_f32(h.x));
            lo.y = bf16_rne(qv.y - bf16_f32(h.y));
            lo.z = bf16_rne(qv.z - bf16_f32(h.z));
            lo.w = bf16_rne(qv.w - bf16_f32(h.w));
            *(short4*)&s_qh[rbase * PB + 4 * d4] = h;
            *(short4*)&s_ql[rbase * PB + 4 * d4] = lo;
        }
        __syncthreads();

        // ---- MFMA: 2 K-steps of 16 ----
        #pragma unroll
        for (int kk = 0; kk < 2; ++kk) {
            const int ao = l31 * PB + 16 * kk + 8 * lh;
            short8v ah = *(const short8v*)&s_qh[ao];
            short8v al = *(const short8v*)&s_ql[ao];
            const int bo0 = (32 * wave + l31) * PB + 16 * kk + 8 * lh;
            short8v bh = *(const short8v*)&s_dh[bo0];
            short8v bl = *(const short8v*)&s_dl[bo0];
            acc0 = __builtin_amdgcn_mfma_f32_32x32x16_bf16(ah, bh, acc0, 0, 0, 0);
            acc0 = __builtin_amdgcn_mfma_f32_32x32x16_bf16(ah, bl, acc0, 0, 0, 0);
            acc0 = __builtin_amdgcn_mfma_f32_32x32x16_bf16(al, bh, acc0, 0, 0, 0);
            if (wave < 2) {
                const int bo1 = (32 * (wave + 4) + l31) * PB + 16 * kk + 8 * lh;
                short8v bh1 = *(const short8v*)&s_dh[bo1];
                short8v bl1 = *(const short8v*)&s_dl[bo1];
                acc1 = __builtin_amdgcn_mfma_f32_32x32x16_bf16(ah, bh1, acc1, 0, 0, 0);
                acc1 = __builtin_amdgcn_mfma_f32_32x32x16_bf16(ah, bl1, acc1, 0, 0, 0);
                acc1 = __builtin_amdgcn_mfma_f32_32x32x16_bf16(al, bh1, acc1, 0, 0, 0);
            }
        }
    }

    // ---- epilogue: per-q-row max over doc tokens ----
    float pm[16];
    #pragma unroll
    for (int r = 0; r < 16; ++r) {
        float v = acc0[r];
        if (wave < 2) v = fmaxf(v, acc1[r]);
        pm[r] = v;
    }
    #pragma unroll
    for (int off = 1; off <= 16; off <<= 1)
        #pragma unroll
        for (int r = 0; r < 16; ++r)
            pm[r] = fmaxf(pm[r], __shfl_xor(pm[r], off));
    if (l31 == 0) {
        #pragma unroll
        for (int r = 0; r < 16; ++r)
            s_pm[wave][(r & 3) + 8 * (r >> 2) + 4 * lh] = pm[r];
    }
    __syncthreads();
    if (t < LQ) {
        float v = fmaxf(fmaxf(s_pm[0][t], s_pm[1][t]),
                        fmaxf(s_pm[2][t], s_pm[3][t]));
        #pragma unroll
        for (int off = 16; off >= 1; off >>= 1) v += __shfl_xor(v, off);
        if (t == 0) scores[bw] = v;
    }
}

// ---------- finisher: log-softmax over W + KLDiv(log_target, batchmean) ----------
__global__ __launch_bounds__(NB) void finish_kernel(
    const float* __restrict__ scores, const float* __restrict__ labels,
    float* __restrict__ out)
{
    __shared__ float s_part[2];
    const int t = threadIdx.x;
    const float* sr = scores + t * NW;
    const float* lr = labels + t * NW;

    float s[NW];
    float m = -INFINITY;
    #pragma unroll
    for (int w = 0; w < NW; ++w) { s[w] = sr[w]; m = fmaxf(m, s[w]); }
    float se = 0.f;
    #pragma unroll
    for (int w = 0; w < NW; ++w) se += expf(s[w] - m);
    float lse = logf(se) + m;

    float term = 0.f;
    #pragma unroll
    for (int w = 0; w < NW; ++w) {
        float lw = lr[w];
        term += expf(lw) * (lw - (s[w] - lse));
    }
    #pragma unroll
    for (int off = 32; off > 0; off >>= 1) term += __shfl_xor(term, off);
    if ((t & 63) == 0) s_part[t >> 6] = term;
    __syncthreads();
    if (t == 0) out[0] = (s_part[0] + s_part[1]) / (float)NB;
}

extern "C" void kernel_launch(void* const* d_in, const int* in_sizes, int n_in,
                              void* d_out, int out_size, void* d_ws, size_t ws_size,
                              hipStream_t stream) {
    const float* qreps  = (const float*)d_in[0];
    const float* dreps  = (const float*)d_in[1];
    const int*   dmask  = (const int*)d_in[2];
    const float* labels = (const float*)d_in[3];
    float* out = (float*)d_out;

    float* scores = (float*)d_ws;       // NBW floats
    float* qinv   = scores + NBW;       // NB*LQ floats

    qnorm_kernel<<<NB, 256, 0, stream>>>(qreps, qinv);
    maxsim_kernel<<<NBW, 256, 0, stream>>>(qreps, dreps, dmask, qinv, scores);
    finish_kernel<<<1, NB, 0, stream>>>(scores, labels, out);
}

// Round 5
// 151.597 us; speedup vs baseline: 1.4852x; 1.0353x over previous
//
#include <hip/hip_runtime.h>
#include <math.h>
#include <stdint.h>

#define NB 128      // batch
#define LQ 32       // query tokens
#define LD 180      // doc tokens
#define DD 128      // feature dim
#define NW 8        // nway
#define NBW (NB*NW)
#define PB 40       // bf16 row pitch (80 B: 16B-aligned rows)
#define LROWS 192   // doc rows padded to 6 tiles of 32 (pad rows zeroed once)

typedef __attribute__((ext_vector_type(8)))  short short8v;
typedef __attribute__((ext_vector_type(16))) float f32x16;

// Barrier WITHOUT vmcnt drain: __syncthreads() emits a workgroup fence that
// waits vmcnt(0), which would stall our cross-barrier global->VGPR prefetch.
// LDS ordering only needs lgkmcnt(0) on both producer and consumer sides.
static __device__ __forceinline__ void bar() {
    asm volatile("s_waitcnt lgkmcnt(0)" ::: "memory");
    __builtin_amdgcn_s_barrier();
}

// truncation-based f32 -> (hi,lo) bf16 split: err ~2^-16 rel, way under budget
static __device__ __forceinline__ void split2(float x, short& h, short& l) {
    uint32_t u = __float_as_uint(x);
    h = (short)(u >> 16);
    float r = x - __uint_as_float(u & 0xffff0000u);
    l = (short)(__float_as_uint(r) >> 16);
}

// ---------- MaxSim: single doc pass, fused q/doc norms, split-bf16 MFMA ----------
// grid NBW x 512 (8 waves, exactly 2 blocks/CU). 4 d-chunks of 32 features:
// stage masked doc as hi/lo bf16 + in-wave shfl ssq; reduce dinv; fold
// qinv*dinv into q' hi/lo; 32x32x16 bf16 MFMA (hh+hl+lh), waves 0..5 own one
// 32-token tile each. Next chunk's doc/q prefetched into regs across bar()s.
__global__ __launch_bounds__(512, 4) void maxsim_kernel(
    const float* __restrict__ qreps, const float* __restrict__ dreps,
    const int* __restrict__ dmask, float* __restrict__ scores)
{
    __shared__ short s_dh[LROWS * PB];   // 15360 B
    __shared__ short s_dl[LROWS * PB];   // 15360 B
    __shared__ short s_qh[LQ * PB];      //  2560 B
    __shared__ short s_ql[LQ * PB];      //  2560 B
    __shared__ float s_ssq[8 * 32];      //  1024 B
    __shared__ float s_dinv[32];
    __shared__ float s_qinv[32];
    __shared__ float s_pm[6][LQ];        //   768 B  (total ~37.9 KB)

    const int t = threadIdx.x, bw = blockIdx.x, b = bw >> 3;
    const int lane = t & 63, wave = t >> 6;
    const int d4 = t & 7;        // feature quad within chunk
    const int rb = t >> 3;       // 0..63: doc row phase
    const int lh = lane >> 5, l31 = lane & 31;

    const float4* doc4 = (const float4*)(dreps + (size_t)bw * LD * DD);
    const float4* q4g  = (const float4*)(qreps + (size_t)b * LQ * DD);
    const int*    mrow = dmask + bw * LD;

    // ---- prefetch chunk-0 doc + q ----
    float4 dv0 = doc4[(rb      ) * 32 + d4];
    float4 dv1 = doc4[(rb + 64 ) * 32 + d4];
    float4 dv2;
    if (rb < 52) dv2 = doc4[(rb + 128) * 32 + d4];
    float4 qv, qn;
    if (t < 256) qv = q4g[(t >> 3) * 32 + d4];

    const float mk0 = (float)mrow[rb];
    const float mk1 = (float)mrow[rb + 64];
    const float mk2 = (rb < 52) ? (float)mrow[rb + 128] : 0.0f;

    // ---- fused query row inv-norms (overlaps doc load latency) ----
    {
        int r = t >> 4, sub = t & 15;
        float4 a = q4g[r * 32 + sub];
        float4 c = q4g[r * 32 + 16 + sub];
        float ss = a.x*a.x + a.y*a.y + a.z*a.z + a.w*a.w
                 + c.x*c.x + c.y*c.y + c.z*c.z + c.w*c.w;
        ss += __shfl_xor(ss, 8);
        ss += __shfl_xor(ss, 4);
        ss += __shfl_xor(ss, 2);
        ss += __shfl_xor(ss, 1);
        if (sub == 0) s_qinv[r] = 1.0f / fmaxf(sqrtf(ss), 1e-12f);
    }

    f32x16 acc = {};

    #pragma unroll
    for (int cc = 0; cc < 4; ++cc) {
        if (cc) bar();            // prev MFMA done reading LDS

        // ---- stage masked doc chunk cc (from prefetched regs) ----
        float4 pssq = make_float4(0.f, 0.f, 0.f, 0.f);
        {
            float4 v = dv0; float m = mk0;
            v.x *= m; v.y *= m; v.z *= m; v.w *= m;
            pssq.x += v.x*v.x; pssq.y += v.y*v.y; pssq.z += v.z*v.z; pssq.w += v.w*v.w;
            short4 h, lo;
            split2(v.x, h.x, lo.x); split2(v.y, h.y, lo.y);
            split2(v.z, h.z, lo.z); split2(v.w, h.w, lo.w);
            *(short4*)&s_dh[rb * PB + 4 * d4] = h;
            *(short4*)&s_dl[rb * PB + 4 * d4] = lo;
        }
        {
            float4 v = dv1; float m = mk1;
            v.x *= m; v.y *= m; v.z *= m; v.w *= m;
            pssq.x += v.x*v.x; pssq.y += v.y*v.y; pssq.z += v.z*v.z; pssq.w += v.w*v.w;
            short4 h, lo;
            split2(v.x, h.x, lo.x); split2(v.y, h.y, lo.y);
            split2(v.z, h.z, lo.z); split2(v.w, h.w, lo.w);
            *(short4*)&s_dh[(rb + 64) * PB + 4 * d4] = h;
            *(short4*)&s_dl[(rb + 64) * PB + 4 * d4] = lo;
        }
        if (rb < 52) {
            float4 v = dv2; float m = mk2;
            v.x *= m; v.y *= m; v.z *= m; v.w *= m;
            pssq.x += v.x*v.x; pssq.y += v.y*v.y; pssq.z += v.z*v.z; pssq.w += v.w*v.w;
            short4 h, lo;
            split2(v.x, h.x, lo.x); split2(v.y, h.y, lo.y);
            split2(v.z, h.z, lo.z); split2(v.w, h.w, lo.w);
            *(short4*)&s_dh[(rb + 128) * PB + 4 * d4] = h;
            *(short4*)&s_dl[(rb + 128) * PB + 4 * d4] = lo;
        } else if (cc == 0) {     // pad rows 180..191: zero once, never rewritten
            short4 z = make_short4(0, 0, 0, 0);
            *(short4*)&s_dh[(rb + 128) * PB + 4 * d4] = z;
            *(short4*)&s_dl[(rb + 128) * PB + 4 * d4] = z;
        }

        // ---- issue next chunk's loads (stay in flight across bar()s) ----
        if (cc < 3) {
            dv0 = doc4[(rb      ) * 32 + (cc + 1) * 8 + d4];
            dv1 = doc4[(rb + 64 ) * 32 + (cc + 1) * 8 + d4];
            if (rb < 52) dv2 = doc4[(rb + 128) * 32 + (cc + 1) * 8 + d4];
            if (t < 256) qn = q4g[(t >> 3) * 32 + (cc + 1) * 8 + d4];
        }

        // ---- ssq: in-wave reduce over the wave's 8 row-groups ----
        #pragma unroll
        for (int off = 8; off <= 32; off <<= 1) {
            pssq.x += __shfl_xor(pssq.x, off);
            pssq.y += __shfl_xor(pssq.y, off);
            pssq.z += __shfl_xor(pssq.z, off);
            pssq.w += __shfl_xor(pssq.w, off);
        }
        if (lane < 8) *(float4*)&s_ssq[wave * 32 + 4 * lane] = pssq;
        bar();

        // ---- per-feature inv-norms ----
        if (t < 32) {
            float tot = 0.f;
            #pragma unroll
            for (int w = 0; w < 8; ++w) tot += s_ssq[w * 32 + t];
            s_dinv[t] = 1.0f / fmaxf(sqrtf(tot), 1e-12f);
        }
        bar();

        // ---- fold qinv*dinv into q', split hi/lo ----
        if (t < 256) {
            float qi = s_qinv[t >> 3];
            float4 di = *(const float4*)&s_dinv[4 * d4];
            float4 v = qv;
            v.x *= qi * di.x; v.y *= qi * di.y;
            v.z *= qi * di.z; v.w *= qi * di.w;
            short4 h, lo;
            split2(v.x, h.x, lo.x); split2(v.y, h.y, lo.y);
            split2(v.z, h.z, lo.z); split2(v.w, h.w, lo.w);
            *(short4*)&s_qh[(t >> 3) * PB + 4 * d4] = h;
            *(short4*)&s_ql[(t >> 3) * PB + 4 * d4] = lo;
        }
        if (cc < 3) qv = qn;
        bar();

        // ---- MFMA: waves 0..5 own one 32-token tile ----
        if (wave < 6) {
            #pragma unroll
            for (int kk = 0; kk < 2; ++kk) {
                int ao = l31 * PB + 16 * kk + 8 * lh;
                short8v ah = *(const short8v*)&s_qh[ao];
                short8v al = *(const short8v*)&s_ql[ao];
                int bo = (32 * wave + l31) * PB + 16 * kk + 8 * lh;
                short8v bh = *(const short8v*)&s_dh[bo];
                short8v bl = *(const short8v*)&s_dl[bo];
                acc = __builtin_amdgcn_mfma_f32_32x32x16_bf16(ah, bh, acc, 0, 0, 0);
                acc = __builtin_amdgcn_mfma_f32_32x32x16_bf16(ah, bl, acc, 0, 0, 0);
                acc = __builtin_amdgcn_mfma_f32_32x32x16_bf16(al, bh, acc, 0, 0, 0);
            }
        }
    }

    // ---- epilogue: per-q-row max over doc tokens, sum over q rows ----
    if (wave < 6) {
        float pm[16];
        #pragma unroll
        for (int r = 0; r < 16; ++r) pm[r] = acc[r];
        #pragma unroll
        for (int off = 1; off <= 16; off <<= 1)
            #pragma unroll
            for (int r = 0; r < 16; ++r)
                pm[r] = fmaxf(pm[r], __shfl_xor(pm[r], off));
        if (l31 == 0) {
            #pragma unroll
            for (int r = 0; r < 16; ++r)
                s_pm[wave][(r & 3) + 8 * (r >> 2) + 4 * lh] = pm[r];
        }
    }
    bar();
    if (t < 32) {
        float v = s_pm[0][t];
        #pragma unroll
        for (int w = 1; w < 6; ++w) v = fmaxf(v, s_pm[w][t]);
        #pragma unroll
        for (int off = 16; off >= 1; off >>= 1) v += __shfl_xor(v, off);
        if (t == 0) scores[bw] = v;
    }
}

// ---------- finisher: log-softmax over W + KLDiv(log_target, batchmean) ----------
__global__ __launch_bounds__(NB) void finish_kernel(
    const float* __restrict__ scores, const float* __restrict__ labels,
    float* __restrict__ out)
{
    __shared__ float s_part[2];
    const int t = threadIdx.x;
    const float* sr = scores + t * NW;
    const float* lr = labels + t * NW;

    float s[NW];
    float m = -INFINITY;
    #pragma unroll
    for (int w = 0; w < NW; ++w) { s[w] = sr[w]; m = fmaxf(m, s[w]); }
    float se = 0.f;
    #pragma unroll
    for (int w = 0; w < NW; ++w) se += expf(s[w] - m);
    float lse = logf(se) + m;

    float term = 0.f;
    #pragma unroll
    for (int w = 0; w < NW; ++w) {
        float lw = lr[w];
        term += expf(lw) * (lw - (s[w] - lse));
    }
    #pragma unroll
    for (int off = 32; off > 0; off >>= 1) term += __shfl_xor(term, off);
    if ((t & 63) == 0) s_part[t >> 6] = term;
    __syncthreads();
    if (t == 0) out[0] = (s_part[0] + s_part[1]) / (float)NB;
}

extern "C" void kernel_launch(void* const* d_in, const int* in_sizes, int n_in,
                              void* d_out, int out_size, void* d_ws, size_t ws_size,
                              hipStream_t stream) {
    const float* qreps  = (const float*)d_in[0];
    const float* dreps  = (const float*)d_in[1];
    const int*   dmask  = (const int*)d_in[2];
    const float* labels = (const float*)d_in[3];
    float* out = (float*)d_out;
    float* scores = (float*)d_ws;   // NBW floats

    maxsim_kernel<<<NBW, 512, 0, stream>>>(qreps, dreps, dmask, scores);
    finish_kernel<<<1, NB, 0, stream>>>(scores, labels, out);
}